// Round 4
// baseline (173.166 us; speedup 1.0000x reference)
//
#include <hip/hip_runtime.h>
#include <hip/hip_bf16.h>

#define VIEWS 16
#define BSZ 512
#define NROWS 8192
#define D 128
#define CSPLIT 16
#define BROWS 256
#define BCOLS 32

typedef short bf16x8 __attribute__((ext_vector_type(8)));
typedef float f32x4 __attribute__((ext_vector_type(4)));

// log2(e)/0.07
constexpr float C1 = 20.609929155556618f;
constexpr float INV_T = 14.285714285714286f;

__device__ __forceinline__ float bf2f(unsigned int u16) {
  return __uint_as_float(u16 << 16);
}

// round-to-nearest-even f32 -> bf16 bits
__device__ __forceinline__ unsigned short f2bf(float f) {
  unsigned int u = __float_as_uint(f);
  u += 0x7fffu + ((u >> 16) & 1u);
  return (unsigned short)(u >> 16);
}

__device__ __forceinline__ float fexp2(float x) {
#if __has_builtin(__builtin_amdgcn_exp2f)
  return __builtin_amdgcn_exp2f(x);
#else
  return exp2f(x);
#endif
}

// K1: normalize rows (fp32), reorder to contrast layout (n = v*512+b <- feature row b*16+v),
// write packed bf16, and write diag[n] = ||bf16 row||^2 (fp32).
__global__ void k_normalize(const float* __restrict__ feat,
                            unsigned int* __restrict__ nrm_u32,
                            float* __restrict__ diag) {
  int gw = (blockIdx.x * blockDim.x + threadIdx.x) >> 6;  // row n
  int lane = threadIdx.x & 63;
  int n = gw;
  int b = n & (BSZ - 1);
  int v = n >> 9;
  const float* src = feat + (size_t)(b * VIEWS + v) * D;
  float2 x = *(const float2*)(src + lane * 2);
  float ss = x.x * x.x + x.y * x.y;
#pragma unroll
  for (int m = 1; m < 64; m <<= 1) ss += __shfl_xor(ss, m);
  float inv = 1.0f / fmaxf(sqrtf(ss), 1e-12f);
  unsigned int u0 = f2bf(x.x * inv);
  unsigned int u1 = f2bf(x.y * inv);
  nrm_u32[(size_t)n * (D / 2) + lane] = (u1 << 16) | u0;
  float a0 = bf2f(u0), a1 = bf2f(u1);
  float ds = a0 * a0 + a1 * a1;
#pragma unroll
  for (int m = 1; m < 64; m <<= 1) ds += __shfl_xor(ds, m);
  if (lane == 0) diag[n] = ds;
}

// K2a: T[b][t] = sum over the 16 views of Nrm[v*512+b][t]
__global__ void k_viewsum(const unsigned short* __restrict__ nrm,
                          float* __restrict__ T) {
  int b = blockIdx.x;
  int t = threadIdx.x;
  float acc = 0.f;
#pragma unroll
  for (int v = 0; v < VIEWS; ++v)
    acc += bf2f(nrm[(size_t)(v * BSZ + b) * D + t]);
  T[(size_t)b * D + t] = acc;
}

// K2b: SV[c] = sum over {b: lbl(b)==c} of T[b]; also cntc[c] = |{b}|.
__global__ void k_svcnt(const float* __restrict__ T,
                        const int* __restrict__ labels,
                        float* __restrict__ sv,
                        int* __restrict__ cntc) {
  __shared__ int lab[BSZ];
  int t = threadIdx.x;
  int c = blockIdx.x;
  for (int i = t; i < BSZ; i += 128) lab[i] = labels[i];
  __syncthreads();
  float acc = 0.f;
  int count = 0;
  for (int b = 0; b < BSZ; ++b) {
    if (lab[b] == c) {
      acc += T[(size_t)b * D + t];
      ++count;
    }
  }
  sv[c * D + t] = acc;
  if (t == 0) cntc[c] = count;
}

// K3: Gram + exp-sum, LDS-staged. 8 waves / 512 threads per block.
// Block owns 256 rows; wave owns 32 rows (afrag[2][4], 32 VGPR).
// B streamed as 32-col tiles through double-buffered LDS (2 x 8KB), shared by
// all 8 waves. T14 split staging: global->reg at top, ds_write after MFMA,
// one barrier per tile. XOR swizzle (row&7)<<4 on write+read kills the
// 16-way bank conflict of the row-major [32][256B] layout.
__global__ __launch_bounds__(512, 4) void k_gram(const short* __restrict__ nrm,
                                                 float* __restrict__ epart) {
  __shared__ __align__(16) char lds_raw[2][BCOLS][256];
  int rowblk = blockIdx.x & 31;  // 32 row-blocks of 256
  int cchunk = blockIdx.x >> 5;  // 0..15
  int tid = threadIdx.x;
  int wid = tid >> 6;
  int lane = tid & 63;
  int idx = lane & 15;
  int kg = lane >> 4;
  int rowbase = rowblk * BROWS + wid * 32;

  // staging addressing: thread stages 16B/tile
  int srow = tid >> 4;                         // 0..31
  int soff = (tid & 15) * 16;                  // 0..240
  int swoff = srow * 256 + (soff ^ ((srow & 7) << 4));  // swizzled LDS byte
  const char* gsrc = (const char*)nrm + (size_t)(cchunk * (NROWS / CSPLIT) + srow) * 256 + soff;

  // A panel: 2 strips x 4 k-chunks, loaded once
  bf16x8 afrag[2][4];
#pragma unroll
  for (int s = 0; s < 2; ++s)
#pragma unroll
    for (int c = 0; c < 4; ++c)
      afrag[s][c] = *(const bf16x8*)(nrm + (size_t)(rowbase + s * 16 + idx) * D + c * 32 + kg * 8);

  // prologue: stage tile 0 into buf 0
  {
    uint4 v = *(const uint4*)gsrc;
    *(uint4*)(&lds_raw[0][0][0] + swoff) = v;
  }

  f32x4 eloc[2][2];
#pragma unroll
  for (int s = 0; s < 2; ++s)
#pragma unroll
    for (int g = 0; g < 2; ++g)
#pragma unroll
      for (int r = 0; r < 4; ++r) eloc[s][g][r] = 0.f;

  __syncthreads();

  const int NT = (NROWS / CSPLIT) / BCOLS;  // 16
  const int rdsw = (idx & 7) << 4;
#pragma unroll 1
  for (int t = 0; t < NT; ++t) {
    // issue next tile's global load early (T14)
    uint4 stage_v;
    if (t + 1 < NT) stage_v = *(const uint4*)(gsrc + (size_t)(t + 1) * BCOLS * 256);

    const char* buf = &lds_raw[t & 1][0][0];
    bf16x8 bfrag[2][4];
#pragma unroll
    for (int g = 0; g < 2; ++g)
#pragma unroll
      for (int c = 0; c < 4; ++c)
        bfrag[g][c] = *(const bf16x8*)(buf + (g * 16 + idx) * 256 + ((c * 64 + kg * 16) ^ rdsw));

#pragma unroll
    for (int s = 0; s < 2; ++s)
#pragma unroll
      for (int g = 0; g < 2; ++g) {
        f32x4 acc = {0.f, 0.f, 0.f, 0.f};
#pragma unroll
        for (int c = 0; c < 4; ++c)
          acc = __builtin_amdgcn_mfma_f32_16x16x32_bf16(afrag[s][c], bfrag[g][c], acc, 0, 0, 0);
#pragma unroll
        for (int r = 0; r < 4; ++r)
          eloc[s][g][r] += fexp2(acc[r] * C1 - C1);
      }

    // write next tile into the other buffer, then one barrier
    if (t + 1 < NT) *(uint4*)(&lds_raw[(t + 1) & 1][0][0] + swoff) = stage_v;
    __syncthreads();
  }

  // sum the two col-groups, reduce across idx lanes (columns), write partials
#pragma unroll
  for (int s = 0; s < 2; ++s)
#pragma unroll
    for (int r = 0; r < 4; ++r) {
      float vv = eloc[s][0][r] + eloc[s][1][r];
      vv += __shfl_xor(vv, 1);
      vv += __shfl_xor(vv, 2);
      vv += __shfl_xor(vv, 4);
      vv += __shfl_xor(vv, 8);
      if (idx == 0)
        epart[(size_t)(rowbase + s * 16 + kg * 4 + r) * CSPLIT + cchunk] = vv;
    }
}

// K4: per-row finish + fused mean via atomicAdd (out zeroed by memset).
__global__ void k_final(const unsigned int* __restrict__ nrm_u32,
                        const float* __restrict__ diag,
                        const float* __restrict__ epart,
                        const float* __restrict__ sv,
                        const int* __restrict__ labels,
                        const int* __restrict__ cntc,
                        float* __restrict__ out) {
  int n = (blockIdx.x * blockDim.x + threadIdx.x) >> 6;
  int lane = threadIdx.x & 63;
  int b = n & (BSZ - 1);
  int lbl = labels[b];
  float2 s2 = *(const float2*)(sv + lbl * D + lane * 2);
  unsigned int u = nrm_u32[(size_t)n * (D / 2) + lane];
  float a0 = bf2f(u & 0xffffu), a1 = bf2f(u >> 16);
  float dot = a0 * s2.x + a1 * s2.y;
  float ep = (lane < CSPLIT) ? epart[(size_t)n * CSPLIT + lane] : 0.f;
#pragma unroll
  for (int m = 1; m < 64; m <<= 1) {
    dot += __shfl_xor(dot, m);
    ep += __shfl_xor(ep, m);
  }
  if (lane == 0) {
    float dii = diag[n];
    float Praw = dot - dii;                       // sum over positives (excl diag) of d_ij
    float Cn = (float)(16 * cntc[lbl] - 1);
    float ediag = fexp2(dii * C1 - C1);
    float Eexcl = ep - ediag;                     // sum_{j!=i} exp(l_ij - 1/T)
    float Sref = Eexcl * fexp2((1.0f - dii) * C1);  // sum_{j!=i} exp(l_ij - m_i)
    float L = logf(Sref + 1e-12f);
    float mlpp = (Praw * INV_T - Cn * (dii * INV_T) - Cn * L) / (Cn + 1e-12f);
    atomicAdd(out, -mlpp * (1.0f / NROWS));
  }
}

extern "C" void kernel_launch(void* const* d_in, const int* in_sizes, int n_in,
                              void* d_out, int out_size, void* d_ws, size_t ws_size,
                              hipStream_t stream) {
  const float* feat = (const float*)d_in[0];
  const int* labels = (const int*)d_in[1];
  float* out = (float*)d_out;
  char* ws = (char*)d_ws;

  size_t off = 0;
  short* nrm = (short*)(ws + off);           off += (size_t)NROWS * D * 2;        // 2 MB
  float* diag = (float*)(ws + off);          off += (size_t)NROWS * 4;            // 32 KB
  float* epart = (float*)(ws + off);         off += (size_t)NROWS * CSPLIT * 4;   // 512 KB
  float* sv = (float*)(ws + off);            off += (size_t)128 * D * 4;          // 64 KB
  int* cntc = (int*)(ws + off);              off += (size_t)128 * 4;              // 512 B
  float* T = (float*)(ws + off);             off += (size_t)BSZ * D * 4;          // 256 KB

  hipMemsetAsync(d_out, 0, sizeof(float), stream);
  k_normalize<<<NROWS / 4, 256, 0, stream>>>(feat, (unsigned int*)nrm, diag);
  k_viewsum<<<BSZ, 128, 0, stream>>>((const unsigned short*)nrm, T);
  k_svcnt<<<100, 128, 0, stream>>>(T, labels, sv, cntc);
  k_gram<<<32 * CSPLIT, 512, 0, stream>>>(nrm, epart);
  k_final<<<NROWS / 4, 256, 0, stream>>>((const unsigned int*)nrm, diag, epart, sv, labels, cntc, out);
}

// Round 5
// 67.801 us; speedup vs baseline: 2.5540x; 2.5540x over previous
//
#include <hip/hip_runtime.h>
#include <hip/hip_bf16.h>

#define VIEWS 16
#define BSZ 512
#define NROWS 8192
#define D 128
#define CSPLIT 16
#define BROWS 256
#define BCOLS 32

typedef short bf16x8 __attribute__((ext_vector_type(8)));
typedef float f32x4 __attribute__((ext_vector_type(4)));

// log2(e)/0.07
constexpr float C1 = 20.609929155556618f;
constexpr float INV_T = 14.285714285714286f;

__device__ __forceinline__ float bf2f(unsigned int u16) {
  return __uint_as_float(u16 << 16);
}

// round-to-nearest-even f32 -> bf16 bits
__device__ __forceinline__ unsigned short f2bf(float f) {
  unsigned int u = __float_as_uint(f);
  u += 0x7fffu + ((u >> 16) & 1u);
  return (unsigned short)(u >> 16);
}

__device__ __forceinline__ float fexp2(float x) {
#if __has_builtin(__builtin_amdgcn_exp2f)
  return __builtin_amdgcn_exp2f(x);
#else
  return exp2f(x);
#endif
}

// K1: normalize rows (fp32), reorder to contrast layout (n = v*512+b <- feature row b*16+v),
// write packed bf16, and write diag[n] = ||bf16 row||^2 (fp32).
__global__ void k_normalize(const float* __restrict__ feat,
                            unsigned int* __restrict__ nrm_u32,
                            float* __restrict__ diag) {
  int gw = (blockIdx.x * blockDim.x + threadIdx.x) >> 6;  // row n
  int lane = threadIdx.x & 63;
  int n = gw;
  int b = n & (BSZ - 1);
  int v = n >> 9;
  const float* src = feat + (size_t)(b * VIEWS + v) * D;
  float2 x = *(const float2*)(src + lane * 2);
  float ss = x.x * x.x + x.y * x.y;
#pragma unroll
  for (int m = 1; m < 64; m <<= 1) ss += __shfl_xor(ss, m);
  float inv = 1.0f / fmaxf(sqrtf(ss), 1e-12f);
  unsigned int u0 = f2bf(x.x * inv);
  unsigned int u1 = f2bf(x.y * inv);
  nrm_u32[(size_t)n * (D / 2) + lane] = (u1 << 16) | u0;
  float a0 = bf2f(u0), a1 = bf2f(u1);
  float ds = a0 * a0 + a1 * a1;
#pragma unroll
  for (int m = 1; m < 64; m <<= 1) ds += __shfl_xor(ds, m);
  if (lane == 0) diag[n] = ds;
}

// K2a: T[b][t] = sum over the 16 views of Nrm[v*512+b][t]
__global__ void k_viewsum(const unsigned short* __restrict__ nrm,
                          float* __restrict__ T) {
  int b = blockIdx.x;
  int t = threadIdx.x;
  float acc = 0.f;
#pragma unroll
  for (int v = 0; v < VIEWS; ++v)
    acc += bf2f(nrm[(size_t)(v * BSZ + b) * D + t]);
  T[(size_t)b * D + t] = acc;
}

// K2b: SV[c] = sum over {b: lbl(b)==c} of T[b]; also cntc[c] = |{b}|.
__global__ void k_svcnt(const float* __restrict__ T,
                        const int* __restrict__ labels,
                        float* __restrict__ sv,
                        int* __restrict__ cntc) {
  __shared__ int lab[BSZ];
  int t = threadIdx.x;
  int c = blockIdx.x;
  for (int i = t; i < BSZ; i += 128) lab[i] = labels[i];
  __syncthreads();
  float acc = 0.f;
  int count = 0;
  for (int b = 0; b < BSZ; ++b) {
    if (lab[b] == c) {
      acc += T[(size_t)b * D + t];
      ++count;
    }
  }
  sv[c * D + t] = acc;
  if (t == 0) cntc[c] = count;
}

// K3: Gram + exp-sum, LDS-staged. 8 waves / 512 threads per block.
// Block owns 256 rows; wave owns 32 rows (afrag[2][4], 32 VGPR).
// B streamed as 32-col tiles through double-buffered LDS (2 x 8KB), shared by
// all 8 waves. T14 split staging: global->reg at top, ds_write after MFMA,
// one barrier per tile. XOR swizzle (row&7)<<4 on write+read kills the
// 16-way bank conflict of the row-major [32][256B] layout.
__global__ __launch_bounds__(512, 4) void k_gram(const short* __restrict__ nrm,
                                                 float* __restrict__ epart) {
  __shared__ __align__(16) char lds_raw[2][BCOLS][256];
  int rowblk = blockIdx.x & 31;  // 32 row-blocks of 256
  int cchunk = blockIdx.x >> 5;  // 0..15
  int tid = threadIdx.x;
  int wid = tid >> 6;
  int lane = tid & 63;
  int idx = lane & 15;
  int kg = lane >> 4;
  int rowbase = rowblk * BROWS + wid * 32;

  // staging addressing: thread stages 16B/tile
  int srow = tid >> 4;                         // 0..31
  int soff = (tid & 15) * 16;                  // 0..240
  int swoff = srow * 256 + (soff ^ ((srow & 7) << 4));  // swizzled LDS byte
  const char* gsrc = (const char*)nrm + (size_t)(cchunk * (NROWS / CSPLIT) + srow) * 256 + soff;

  // A panel: 2 strips x 4 k-chunks, loaded once
  bf16x8 afrag[2][4];
#pragma unroll
  for (int s = 0; s < 2; ++s)
#pragma unroll
    for (int c = 0; c < 4; ++c)
      afrag[s][c] = *(const bf16x8*)(nrm + (size_t)(rowbase + s * 16 + idx) * D + c * 32 + kg * 8);

  // prologue: stage tile 0 into buf 0
  {
    uint4 v = *(const uint4*)gsrc;
    *(uint4*)(&lds_raw[0][0][0] + swoff) = v;
  }

  f32x4 eloc[2][2];
#pragma unroll
  for (int s = 0; s < 2; ++s)
#pragma unroll
    for (int g = 0; g < 2; ++g)
#pragma unroll
      for (int r = 0; r < 4; ++r) eloc[s][g][r] = 0.f;

  __syncthreads();

  const int NT = (NROWS / CSPLIT) / BCOLS;  // 16
  const int rdsw = (idx & 7) << 4;
#pragma unroll 1
  for (int t = 0; t < NT; ++t) {
    // issue next tile's global load early (T14)
    uint4 stage_v;
    if (t + 1 < NT) stage_v = *(const uint4*)(gsrc + (size_t)(t + 1) * BCOLS * 256);

    const char* buf = &lds_raw[t & 1][0][0];
    bf16x8 bfrag[2][4];
#pragma unroll
    for (int g = 0; g < 2; ++g)
#pragma unroll
      for (int c = 0; c < 4; ++c)
        bfrag[g][c] = *(const bf16x8*)(buf + (g * 16 + idx) * 256 + ((c * 64 + kg * 16) ^ rdsw));

#pragma unroll
    for (int s = 0; s < 2; ++s)
#pragma unroll
      for (int g = 0; g < 2; ++g) {
        f32x4 acc = {0.f, 0.f, 0.f, 0.f};
#pragma unroll
        for (int c = 0; c < 4; ++c)
          acc = __builtin_amdgcn_mfma_f32_16x16x32_bf16(afrag[s][c], bfrag[g][c], acc, 0, 0, 0);
#pragma unroll
        for (int r = 0; r < 4; ++r)
          eloc[s][g][r] += fexp2(acc[r] * C1 - C1);
      }

    // write next tile into the other buffer, then one barrier
    if (t + 1 < NT) *(uint4*)(&lds_raw[(t + 1) & 1][0][0] + swoff) = stage_v;
    __syncthreads();
  }

  // sum the two col-groups, reduce across idx lanes (columns), write partials
#pragma unroll
  for (int s = 0; s < 2; ++s)
#pragma unroll
    for (int r = 0; r < 4; ++r) {
      float vv = eloc[s][0][r] + eloc[s][1][r];
      vv += __shfl_xor(vv, 1);
      vv += __shfl_xor(vv, 2);
      vv += __shfl_xor(vv, 4);
      vv += __shfl_xor(vv, 8);
      if (idx == 0)
        epart[(size_t)(rowbase + s * 16 + kg * 4 + r) * CSPLIT + cchunk] = vv;
    }
}

// K4: per-row finish. one wave per row; writes lossb[n] (no atomics).
__global__ void k_final(const unsigned int* __restrict__ nrm_u32,
                        const float* __restrict__ diag,
                        const float* __restrict__ epart,
                        const float* __restrict__ sv,
                        const int* __restrict__ labels,
                        const int* __restrict__ cntc,
                        float* __restrict__ lossb) {
  int n = (blockIdx.x * blockDim.x + threadIdx.x) >> 6;
  int lane = threadIdx.x & 63;
  int b = n & (BSZ - 1);
  int lbl = labels[b];
  float2 s2 = *(const float2*)(sv + lbl * D + lane * 2);
  unsigned int u = nrm_u32[(size_t)n * (D / 2) + lane];
  float a0 = bf2f(u & 0xffffu), a1 = bf2f(u >> 16);
  float dot = a0 * s2.x + a1 * s2.y;
  float ep = (lane < CSPLIT) ? epart[(size_t)n * CSPLIT + lane] : 0.f;
#pragma unroll
  for (int m = 1; m < 64; m <<= 1) {
    dot += __shfl_xor(dot, m);
    ep += __shfl_xor(ep, m);
  }
  if (lane == 0) {
    float dii = diag[n];
    float Praw = dot - dii;                       // sum over positives (excl diag) of d_ij
    float Cn = (float)(16 * cntc[lbl] - 1);
    float ediag = fexp2(dii * C1 - C1);
    float Eexcl = ep - ediag;                     // sum_{j!=i} exp(l_ij - 1/T)
    float Sref = Eexcl * fexp2((1.0f - dii) * C1);  // sum_{j!=i} exp(l_ij - m_i)
    float L = logf(Sref + 1e-12f);
    float mlpp = (Praw * INV_T - Cn * (dii * INV_T) - Cn * L) / (Cn + 1e-12f);
    lossb[n] = -mlpp;
  }
}

// K5: mean over 8192 losses -> scalar (single block, no atomics)
__global__ void k_reduce(const float* __restrict__ lossb, float* __restrict__ out) {
  float s = 0.f;
  for (int i = threadIdx.x; i < NROWS; i += 1024) s += lossb[i];
#pragma unroll
  for (int m = 1; m < 64; m <<= 1) s += __shfl_xor(s, m);
  __shared__ float partial[16];
  int w = threadIdx.x >> 6, l = threadIdx.x & 63;
  if (l == 0) partial[w] = s;
  __syncthreads();
  if (threadIdx.x < 16) {
    float vv = partial[threadIdx.x];
#pragma unroll
    for (int m = 1; m < 16; m <<= 1) vv += __shfl_xor(vv, m);
    if (threadIdx.x == 0) out[0] = vv * (1.0f / NROWS);
  }
}

extern "C" void kernel_launch(void* const* d_in, const int* in_sizes, int n_in,
                              void* d_out, int out_size, void* d_ws, size_t ws_size,
                              hipStream_t stream) {
  const float* feat = (const float*)d_in[0];
  const int* labels = (const int*)d_in[1];
  float* out = (float*)d_out;
  char* ws = (char*)d_ws;

  size_t off = 0;
  short* nrm = (short*)(ws + off);           off += (size_t)NROWS * D * 2;        // 2 MB
  float* diag = (float*)(ws + off);          off += (size_t)NROWS * 4;            // 32 KB
  float* epart = (float*)(ws + off);         off += (size_t)NROWS * CSPLIT * 4;   // 512 KB
  float* sv = (float*)(ws + off);            off += (size_t)128 * D * 4;          // 64 KB
  int* cntc = (int*)(ws + off);              off += (size_t)128 * 4;              // 512 B
  float* T = (float*)(ws + off);             off += (size_t)BSZ * D * 4;          // 256 KB
  float* lossb = (float*)(ws + off);         off += (size_t)NROWS * 4;            // 32 KB

  k_normalize<<<NROWS / 4, 256, 0, stream>>>(feat, (unsigned int*)nrm, diag);
  k_viewsum<<<BSZ, 128, 0, stream>>>((const unsigned short*)nrm, T);
  k_svcnt<<<100, 128, 0, stream>>>(T, labels, sv, cntc);
  k_gram<<<32 * CSPLIT, 512, 0, stream>>>(nrm, epart);
  k_final<<<NROWS / 4, 256, 0, stream>>>((const unsigned int*)nrm, diag, epart, sv, labels, cntc, lossb);
  k_reduce<<<1, 1024, 0, stream>>>(lossb, out);
}